// Round 13
// baseline (91.648 us; speedup 1.0000x reference)
//
#include <hip/hip_runtime.h>
#include <math.h>

#define D_MODEL 512
#define N_HEADS 8
#define DH      64
#define S_LEN   3072
#define BATCH   2
#define KMAX    32
#define M_ROWS  6144
#define CAND_CAP 512
#define NBUCKET 1024                             // 2 batches x 512 morton cells

#define TOPK_BLOCKS (M_ROWS / 4)                 // 1536 (4 rows per block)
#define CONV_BLOCKS (M_ROWS * D_MODEL / 1024)    // 3072
#define PACK_BLOCKS 2048
#define PREP_BLOCKS (TOPK_BLOCKS + CONV_BLOCKS + PACK_BLOCKS + 1)  // +1 morton

typedef __attribute__((ext_vector_type(8))) short bf16x8;
typedef __attribute__((ext_vector_type(4))) float f32x4;
typedef __attribute__((ext_vector_type(2))) short s16x2;
typedef unsigned long long u64;

__device__ __forceinline__ float b2f(unsigned int u) {
    return __uint_as_float((u & 0xFFFFu) << 16);
}
__device__ __forceinline__ unsigned short f2b(float f) {
    unsigned int u = __float_as_uint(f);
    return (unsigned short)((u + 0x7FFFu + ((u >> 16) & 1u)) >> 16);  // RNE
}
__device__ __forceinline__ int mcell(float v) {
    int c = (int)((v + 2.0f) * 2.0f);            // cell width 0.5 over [-2,2)
    return c < 0 ? 0 : (c > 7 ? 7 : c);
}
__device__ __forceinline__ int morton3(int cx, int cy, int cz) {
    int k = 0;
    #pragma unroll
    for (int b = 0; b < 3; ++b)
        k |= ((cx >> b) & 1) << (3 * b)
           | ((cy >> b) & 1) << (3 * b + 1)
           | ((cz >> b) & 1) << (3 * b + 2);
    return k;
}

#if __has_builtin(__builtin_amdgcn_fdot2_f32_bf16)
__device__ __forceinline__ float dot2bf(unsigned int a, unsigned int b, float c) {
    return __builtin_amdgcn_fdot2_f32_bf16(
        __builtin_bit_cast(s16x2, a), __builtin_bit_cast(s16x2, b), c, false);
}
#else
__device__ __forceinline__ float dot2bf(unsigned int a, unsigned int b, float c) {
    return c + b2f(a) * b2f(b) + b2f(a >> 16) * b2f(b >> 16);
}
#endif

// ---------------------------------------------------------------------------
// prep: fused topk (4 rows/block) | x->bf16 | weight pack | morton (1 block).
// ---------------------------------------------------------------------------
__global__ __launch_bounds__(256) void prep_kernel(
    const float* __restrict__ x, const float* __restrict__ pos,
    const float* __restrict__ Wq, const float* __restrict__ bq,
    const float* __restrict__ Wk, const float* __restrict__ bk,
    const float* __restrict__ Wv, const float* __restrict__ bv,
    const float* __restrict__ Wo,
    unsigned short* __restrict__ xb, unsigned short* __restrict__ Wt,
    float* __restrict__ bqkv,
    int* __restrict__ nbr_idx, int* __restrict__ nbr_cnt,
    int* __restrict__ order)
{
    const int bid = blockIdx.x;
    const int tid = threadIdx.x;

    if (bid < TOPK_BLOCKS) {
        __shared__ u64 s_keys[4][CAND_CAP];
        __shared__ int s_n[4];
        const int r0 = bid * 4;
        const int b = (r0 >= S_LEN) ? 1 : 0;
        if (tid < 4) s_n[tid] = 0;
        __syncthreads();

        float qx[4], qy[4], qz[4];
        #pragma unroll
        for (int r = 0; r < 4; ++r) {
            qx[r] = pos[(size_t)(r0 + r) * 3 + 0];
            qy[r] = pos[(size_t)(r0 + r) * 3 + 1];
            qz[r] = pos[(size_t)(r0 + r) * 3 + 2];
        }
        const float* pb = pos + (size_t)b * S_LEN * 3;
        #pragma unroll
        for (int i = 0; i < 12; ++i) {
            const int t = tid + i * 256;
            const float x3 = pb[t * 3 + 0], y3 = pb[t * 3 + 1], z3 = pb[t * 3 + 2];
            #pragma unroll
            for (int r = 0; r < 4; ++r) {
                const float dx = qx[r] - x3, dy = qy[r] - y3, dz = qz[r] - z3;
                const float d2 = dx * dx + dy * dy + dz * dz;
                if (d2 < 0.25f) {
                    const int slot = atomicAdd(&s_n[r], 1);
                    if (slot < CAND_CAP)
                        s_keys[r][slot] = ((u64)__float_as_uint(d2) << 32) | (unsigned)t;
                }
            }
        }
        __syncthreads();

        const int rr = tid >> 6, c0 = tid & 63;
        const int n = min(s_n[rr], CAND_CAP);
        for (int c = c0; c < n; c += 64) {
            const u64 k = s_keys[rr][c];
            int rank = 0;
            for (int j = 0; j < n; ++j) rank += (s_keys[rr][j] < k) ? 1 : 0;
            if (rank < KMAX)
                nbr_idx[(size_t)(r0 + rr) * KMAX + rank] = (int)(k & 0xFFFFFFFFu);
        }
        if (c0 == 0) nbr_cnt[r0 + rr] = min(n, KMAX);
    } else if (bid < TOPK_BLOCKS + CONV_BLOCKS) {
        const int i = ((bid - TOPK_BLOCKS) * 256 + tid) * 4;
        const float4 v = *reinterpret_cast<const float4*>(x + i);
        ushort4 o;
        o.x = f2b(v.x); o.y = f2b(v.y); o.z = f2b(v.z); o.w = f2b(v.w);
        *reinterpret_cast<ushort4*>(xb + i) = o;
    } else if (bid < TOPK_BLOCKS + CONV_BLOCKS + PACK_BLOCKS) {
        const int n = bid - TOPK_BLOCKS - CONV_BLOCKS;
        const float* W; int nn;
        if (n < 512)       { W = Wq; nn = n; }
        else if (n < 1024) { W = Wk; nn = n - 512; }
        else if (n < 1536) { W = Wv; nn = n - 1024; }
        else               { W = Wo; nn = n - 1536; }
        for (int k = tid; k < 512; k += 256)
            Wt[(size_t)n * 512 + k] = f2b(W[(size_t)k * 512 + nn]);
        if (tid == 0 && n < 1536) {
            const float* bsel = (n < 512) ? bq : (n < 1024) ? bk : bv;
            bqkv[n] = bsel[nn];
        }
    } else {
        // ---- morton order (single block): LDS hist -> 1-wave scan -> slots ----
        __shared__ int hist[NBUCKET];
        __shared__ int offs[NBUCKET];
        #pragma unroll
        for (int i = 0; i < NBUCKET / 256; ++i) hist[tid + i * 256] = 0;
        __syncthreads();

        int bkt[24];
        #pragma unroll
        for (int i = 0; i < 24; ++i) {
            const int row = tid + i * 256;
            const int b2 = (row >= S_LEN) ? 1 : 0;
            const float px = pos[(size_t)row * 3 + 0];
            const float py = pos[(size_t)row * 3 + 1];
            const float pz = pos[(size_t)row * 3 + 2];
            bkt[i] = b2 * 512 + morton3(mcell(px), mcell(py), mcell(pz));
            atomicAdd(&hist[bkt[i]], 1);
        }
        __syncthreads();

        if (tid < 64) {   // exclusive scan over 1024 entries: 16 buckets/lane
            const int base = tid * 16;
            int loc[16];
            int s = 0;
            #pragma unroll
            for (int k = 0; k < 16; ++k) { loc[k] = hist[base + k]; s += loc[k]; }
            int inc = s;
            #pragma unroll
            for (int off = 1; off < 64; off <<= 1) {
                const int t = __shfl_up(inc, off, 64);
                if (tid >= off) inc += t;
            }
            int excl = inc - s;
            #pragma unroll
            for (int k = 0; k < 16; ++k) { offs[base + k] = excl; excl += loc[k]; }
        }
        __syncthreads();

        #pragma unroll
        for (int i = 0; i < 24; ++i) {
            const int row = tid + i * 256;
            const int slot = atomicAdd(&offs[bkt[i]], 1);
            order[slot] = row;
        }
    }
}

// ---------------------------------------------------------------------------
// bf16 MFMA GEMM: C[m][n] = sum_k A[m][k] * Bt[n][k] + bias[n]
// 128x128 tile, 4 waves 2x2, BK=32, global_load_lds width-16 staging.
// ---------------------------------------------------------------------------
template <bool OUT_BF16>
__global__ __launch_bounds__(256) void gemm_mfma_kernel(
    const unsigned short* __restrict__ A,
    const unsigned short* __restrict__ Bt,
    const float* __restrict__ bias,
    void* __restrict__ Cv, int ldc)
{
    constexpr int K = 512;
    __shared__ __align__(16) unsigned short As[128 * 32];
    __shared__ __align__(16) unsigned short Bs[128 * 32];

    const int tid = threadIdx.x;
    const int m0 = blockIdx.x * 128;
    const int n0 = blockIdx.y * 128;
    const int wid = tid >> 6;
    const int lane = tid & 63;
    const int wm = (wid >> 1) * 64;
    const int wn = (wid & 1) * 64;
    const int l15 = lane & 15;
    const int kg = lane >> 4;

    const int srow = tid >> 2;
    const int sk = (tid & 3) * 8;

    f32x4 acc[4][4] = {};

    for (int kt = 0; kt < K; kt += 32) {
        #pragma unroll
        for (int c = 0; c < 2; ++c) {
            const unsigned short* ga = A + (size_t)(m0 + c * 64 + srow) * K + kt + sk;
            __builtin_amdgcn_global_load_lds(
                (const __attribute__((address_space(1))) void*)ga,
                (__attribute__((address_space(3))) void*)(&As[c * 2048 + tid * 8]),
                16, 0, 0);
            const unsigned short* gb = Bt + (size_t)(n0 + c * 64 + srow) * K + kt + sk;
            __builtin_amdgcn_global_load_lds(
                (const __attribute__((address_space(1))) void*)gb,
                (__attribute__((address_space(3))) void*)(&Bs[c * 2048 + tid * 8]),
                16, 0, 0);
        }
        __syncthreads();

        bf16x8 af[4], bfr[4];
        #pragma unroll
        for (int i = 0; i < 4; ++i) {
            af[i]  = *reinterpret_cast<const bf16x8*>(&As[(wm + i * 16 + l15) * 32 + kg * 8]);
            bfr[i] = *reinterpret_cast<const bf16x8*>(&Bs[(wn + i * 16 + l15) * 32 + kg * 8]);
        }
        #pragma unroll
        for (int i = 0; i < 4; ++i)
            #pragma unroll
            for (int j = 0; j < 4; ++j)
                acc[i][j] = __builtin_amdgcn_mfma_f32_16x16x32_bf16(af[i], bfr[j], acc[i][j], 0, 0, 0);
        __syncthreads();
    }

    const int crow = kg * 4;
    #pragma unroll
    for (int i = 0; i < 4; ++i) {
        #pragma unroll
        for (int j = 0; j < 4; ++j) {
            const int col = n0 + wn + j * 16 + l15;
            const float bb = bias[col];
            #pragma unroll
            for (int r = 0; r < 4; ++r) {
                const int row = m0 + wm + i * 16 + crow + r;
                const float v = acc[i][j][r] + bb;
                if (OUT_BF16)
                    ((unsigned short*)Cv)[(size_t)row * ldc + col] = f2b(v);
                else
                    ((float*)Cv)[(size_t)row * ldc + col] = v;
            }
        }
    }
}

// ---------------------------------------------------------------------------
// Sparse attention (R8 structure + morton-ordered block->row mapping).
// Co-resident blocks cover a compact 3D cell, so the union of their
// neighbor balls (~1.5-2.5 MB of K/V) fits the 4 MB per-XCD L2 -- unlike the
// z-slab whose +-0.5 halo exceeded it. K staged via coalesced
// global_load_lds; V coalesced 128B per neighbor, in flight alongside.
// Packed bf16 dot2 score/PV.
// ---------------------------------------------------------------------------
__global__ __launch_bounds__(512) void attn_kernel(
    const unsigned short* __restrict__ qkv,
    const int* __restrict__ nbr_idx,
    const int* __restrict__ nbr_cnt,
    const int* __restrict__ order,
    unsigned short* __restrict__ ao)
{
    const int row = order[blockIdx.x];
    const int b = (row >= S_LEN) ? 1 : 0;
    const int tid = threadIdx.x;
    const int h = tid >> 6;
    const int lane = tid & 63;
    const int j = lane & 31;
    const int half = lane >> 5;

    __shared__ __align__(16) unsigned short K_lds[KMAX][520];  // 33,280 B
    __shared__ unsigned int s_off[KMAX];
    __shared__ unsigned int sQ[N_HEADS][32];
    __shared__ int s_cnt;

    if (tid < KMAX) {
        const int cnt0 = nbr_cnt[row];
        int t = nbr_idx[(size_t)row * KMAX + tid];
        t = (tid < cnt0) ? t : 0;
        s_off[tid] = (unsigned int)t * 3072u;   // qkv row bytes
        if (tid == 0) s_cnt = cnt0;
    }
    if (lane < 32)   // packed bf16 Q per head
        sQ[h][lane] = ((const unsigned int*)(qkv + (size_t)row * 1536 + h * DH))[lane];
    __syncthreads();

    const int cnt = s_cnt;
    const char* qkvb_ = (const char*)qkv + (size_t)b * S_LEN * 3072;

    // --- K staging: wave h stages neighbor rows h*4..h*4+3 (1 KB each) ---
    {
        const int jb = h * 4;
        #pragma unroll
        for (int c = 0; c < 4; ++c) {
            const int jj = jb + c;
            const char* src = qkvb_ + s_off[jj] + 1024 + lane * 16;
            __builtin_amdgcn_global_load_lds(
                (const __attribute__((address_space(1))) void*)src,
                (__attribute__((address_space(3))) void*)(&K_lds[jj][0]),
                16, 0, 0);
        }
    }

    // --- V prefetch from global (coalesced 128 B per neighbor) ---
    const char* vbase_l = qkvb_ + 2048 + h * 128 + lane * 2;
    unsigned int vr[KMAX];
    #pragma unroll
    for (int jj = 0; jj < KMAX; ++jj)
        vr[jj] = *(const unsigned short*)(vbase_l + s_off[jj]);

    __syncthreads();   // drains vmcnt (staging + V) before LDS reads

    // --- score: lane (half, j) reads 32 dims of neighbor j's K from LDS ---
    const uint4* kp = reinterpret_cast<const uint4*>(&K_lds[j][h * 64 + half * 32]);
    uint4 ku[4];
    #pragma unroll
    for (int c = 0; c < 4; ++c) ku[c] = kp[c];

    const unsigned int* qws = &sQ[h][half * 16];
    float partial = 0.f;
    #pragma unroll
    for (int c = 0; c < 4; ++c) {
        partial = dot2bf(ku[c].x, qws[c * 4 + 0], partial);
        partial = dot2bf(ku[c].y, qws[c * 4 + 1], partial);
        partial = dot2bf(ku[c].z, qws[c * 4 + 2], partial);
        partial = dot2bf(ku[c].w, qws[c * 4 + 3], partial);
    }
    partial += __shfl_down(partial, 32, 64);   // lanes 0..31 hold full dots

    // --- softmax over lanes 0..31 ---
    const float sc = (half == 0 && j < cnt) ? partial * 0.125f : -INFINITY;
    float mx = sc;
    #pragma unroll
    for (int off = 16; off; off >>= 1) mx = fmaxf(mx, __shfl_xor(mx, off, 64));
    const float pr = (half == 0 && j < cnt) ? expf(sc - mx) : 0.f;
    float sum = pr;
    #pragma unroll
    for (int off = 16; off; off >>= 1) sum += __shfl_xor(sum, off, 64);
    const float inv = __uint_as_float(
        __builtin_amdgcn_readfirstlane(__float_as_uint(1.f / sum)));

    // --- weights -> packed bf16 pairs ---
    const float pn = __shfl_xor(pr, 1, 64);
    const unsigned int pw = ((unsigned int)f2b(pn) << 16) | f2b(pr);

    // --- PV: per 2 neighbors: 1 readlane + 1 pack + 1 dot2 ---
    float o0 = 0.f, o1 = 0.f;
    #pragma unroll
    for (int i = 0; i < 16; i += 2) {
        const unsigned int w0 = __builtin_amdgcn_readlane(pw, 2 * i);
        const unsigned int w1 = __builtin_amdgcn_readlane(pw, 2 * i + 2);
        const unsigned int vp0 = (vr[2 * i + 1] << 16) | vr[2 * i];
        const unsigned int vp1 = (vr[2 * i + 3] << 16) | vr[2 * i + 2];
        o0 = dot2bf(vp0, w0, o0);
        o1 = dot2bf(vp1, w1, o1);
    }
    const float o = (o0 + o1) * inv;
    ao[(size_t)row * D_MODEL + h * DH + lane] = f2b(o);
}

// ---------------------------------------------------------------------------
extern "C" void kernel_launch(void* const* d_in, const int* in_sizes, int n_in,
                              void* d_out, int out_size, void* d_ws, size_t ws_size,
                              hipStream_t stream) {
    const float* x   = (const float*)d_in[0];
    const float* pos = (const float*)d_in[1];
    const float* Wq  = (const float*)d_in[2];
    const float* bq  = (const float*)d_in[3];
    const float* Wk  = (const float*)d_in[4];
    const float* bk  = (const float*)d_in[5];
    const float* Wv  = (const float*)d_in[6];
    const float* bv  = (const float*)d_in[7];
    const float* Wo  = (const float*)d_in[8];
    const float* bo  = (const float*)d_in[9];
    float* out = (float*)d_out;

    unsigned short* xb   = (unsigned short*)d_ws;                 // 6144*512
    unsigned short* Wt   = xb + (size_t)M_ROWS * 512;             // 2048*512
    float*          bqkv = (float*)(Wt + (size_t)2048 * 512);     // 1536
    unsigned short* qkvb = (unsigned short*)(bqkv + 1536);        // 6144*1536
    unsigned short* aob  = qkvb + (size_t)M_ROWS * 1536;          // 6144*512
    int*            nidx = (int*)(aob + (size_t)M_ROWS * 512);    // 6144*32
    int*            ncnt = nidx + (size_t)M_ROWS * KMAX;          // 6144
    int*            ordr = ncnt + M_ROWS;                         // 6144

    prep_kernel<<<PREP_BLOCKS, 256, 0, stream>>>(
        x, pos, Wq, bq, Wk, bk, Wv, bv, Wo, xb, Wt, bqkv, nidx, ncnt, ordr);

    dim3 g1(M_ROWS / 128, 1536 / 128);
    gemm_mfma_kernel<true><<<g1, 256, 0, stream>>>(xb, Wt, bqkv, qkvb, 1536);

    attn_kernel<<<M_ROWS, 512, 0, stream>>>(qkvb, nidx, ncnt, ordr, aob);

    dim3 g2(M_ROWS / 128, 512 / 128);
    gemm_mfma_kernel<false><<<g2, 256, 0, stream>>>(aob, Wt + (size_t)1536 * 512, bo, out, 512);
}

// Round 14
// 81.529 us; speedup vs baseline: 1.1241x; 1.1241x over previous
//
#include <hip/hip_runtime.h>
#include <math.h>

#define D_MODEL 512
#define N_HEADS 8
#define DH      64
#define S_LEN   3072
#define BATCH   2
#define KMAX    32
#define M_ROWS  6144
#define CAND_CAP 512

#define TOPK_BLOCKS (M_ROWS / 4)                 // 1536 (4 rows per block)
#define CONV_BLOCKS (M_ROWS * D_MODEL / 1024)    // 3072
#define PACK_BLOCKS 2048
#define PREP_BLOCKS (TOPK_BLOCKS + CONV_BLOCKS + PACK_BLOCKS)

typedef __attribute__((ext_vector_type(8))) short bf16x8;
typedef __attribute__((ext_vector_type(4))) float f32x4;
typedef __attribute__((ext_vector_type(2))) short s16x2;
typedef unsigned long long u64;

__device__ __forceinline__ float b2f(unsigned int u) {
    return __uint_as_float((u & 0xFFFFu) << 16);
}
__device__ __forceinline__ unsigned short f2b(float f) {
    unsigned int u = __float_as_uint(f);
    return (unsigned short)((u + 0x7FFFu + ((u >> 16) & 1u)) >> 16);  // RNE
}

#if __has_builtin(__builtin_amdgcn_fdot2_f32_bf16)
__device__ __forceinline__ float dot2bf(unsigned int a, unsigned int b, float c) {
    return __builtin_amdgcn_fdot2_f32_bf16(
        __builtin_bit_cast(s16x2, a), __builtin_bit_cast(s16x2, b), c, false);
}
#else
__device__ __forceinline__ float dot2bf(unsigned int a, unsigned int b, float c) {
    return c + b2f(a) * b2f(b) + b2f(a >> 16) * b2f(b >> 16);
}
#endif

// ---------------------------------------------------------------------------
// prep: fused topk (4 rows/block) | x->bf16 | weight transpose+pack.
// ---------------------------------------------------------------------------
__global__ __launch_bounds__(256) void prep_kernel(
    const float* __restrict__ x, const float* __restrict__ pos,
    const float* __restrict__ Wq, const float* __restrict__ bq,
    const float* __restrict__ Wk, const float* __restrict__ bk,
    const float* __restrict__ Wv, const float* __restrict__ bv,
    const float* __restrict__ Wo,
    unsigned short* __restrict__ xb, unsigned short* __restrict__ Wt,
    float* __restrict__ bqkv,
    int* __restrict__ nbr_idx, int* __restrict__ nbr_cnt)
{
    const int bid = blockIdx.x;
    const int tid = threadIdx.x;

    if (bid < TOPK_BLOCKS) {
        __shared__ u64 s_keys[4][CAND_CAP];
        __shared__ int s_n[4];
        const int r0 = bid * 4;
        const int b = (r0 >= S_LEN) ? 1 : 0;
        if (tid < 4) s_n[tid] = 0;
        __syncthreads();

        float qx[4], qy[4], qz[4];
        #pragma unroll
        for (int r = 0; r < 4; ++r) {
            qx[r] = pos[(size_t)(r0 + r) * 3 + 0];
            qy[r] = pos[(size_t)(r0 + r) * 3 + 1];
            qz[r] = pos[(size_t)(r0 + r) * 3 + 2];
        }
        const float* pb = pos + (size_t)b * S_LEN * 3;
        #pragma unroll
        for (int i = 0; i < 12; ++i) {
            const int t = tid + i * 256;
            const float x3 = pb[t * 3 + 0], y3 = pb[t * 3 + 1], z3 = pb[t * 3 + 2];
            #pragma unroll
            for (int r = 0; r < 4; ++r) {
                const float dx = qx[r] - x3, dy = qy[r] - y3, dz = qz[r] - z3;
                const float d2 = dx * dx + dy * dy + dz * dz;
                if (d2 < 0.25f) {
                    const int slot = atomicAdd(&s_n[r], 1);
                    if (slot < CAND_CAP)
                        s_keys[r][slot] = ((u64)__float_as_uint(d2) << 32) | (unsigned)t;
                }
            }
        }
        __syncthreads();

        const int rr = tid >> 6, c0 = tid & 63;
        const int n = min(s_n[rr], CAND_CAP);
        for (int c = c0; c < n; c += 64) {
            const u64 k = s_keys[rr][c];
            int rank = 0;
            for (int j = 0; j < n; ++j) rank += (s_keys[rr][j] < k) ? 1 : 0;
            if (rank < KMAX)
                nbr_idx[(size_t)(r0 + rr) * KMAX + rank] = (int)(k & 0xFFFFFFFFu);
        }
        if (c0 == 0) nbr_cnt[r0 + rr] = min(n, KMAX);
    } else if (bid < TOPK_BLOCKS + CONV_BLOCKS) {
        const int i = ((bid - TOPK_BLOCKS) * 256 + tid) * 4;
        const float4 v = *reinterpret_cast<const float4*>(x + i);
        ushort4 o;
        o.x = f2b(v.x); o.y = f2b(v.y); o.z = f2b(v.z); o.w = f2b(v.w);
        *reinterpret_cast<ushort4*>(xb + i) = o;
    } else {
        const int n = bid - TOPK_BLOCKS - CONV_BLOCKS;
        const float* W; int nn;
        if (n < 512)       { W = Wq; nn = n; }
        else if (n < 1024) { W = Wk; nn = n - 512; }
        else if (n < 1536) { W = Wv; nn = n - 1024; }
        else               { W = Wo; nn = n - 1536; }
        for (int k = tid; k < 512; k += 256)
            Wt[(size_t)n * 512 + k] = f2b(W[(size_t)k * 512 + nn]);
        if (tid == 0 && n < 1536) {
            const float* bsel = (n < 512) ? bq : (n < 1024) ? bk : bv;
            bqkv[n] = bsel[nn];
        }
    }
}

// ---------------------------------------------------------------------------
// bf16 MFMA GEMM: C[m][n] = sum_k A[m][k] * Bt[n][k] + bias[n]
// 128x128 tile, 4 waves 2x2, BK=32, global_load_lds width-16 staging.
// ---------------------------------------------------------------------------
template <bool OUT_BF16>
__global__ __launch_bounds__(256) void gemm_mfma_kernel(
    const unsigned short* __restrict__ A,
    const unsigned short* __restrict__ Bt,
    const float* __restrict__ bias,
    void* __restrict__ Cv, int ldc)
{
    constexpr int K = 512;
    __shared__ __align__(16) unsigned short As[128 * 32];
    __shared__ __align__(16) unsigned short Bs[128 * 32];

    const int tid = threadIdx.x;
    const int m0 = blockIdx.x * 128;
    const int n0 = blockIdx.y * 128;
    const int wid = tid >> 6;
    const int lane = tid & 63;
    const int wm = (wid >> 1) * 64;
    const int wn = (wid & 1) * 64;
    const int l15 = lane & 15;
    const int kg = lane >> 4;

    const int srow = tid >> 2;
    const int sk = (tid & 3) * 8;

    f32x4 acc[4][4] = {};

    for (int kt = 0; kt < K; kt += 32) {
        #pragma unroll
        for (int c = 0; c < 2; ++c) {
            const unsigned short* ga = A + (size_t)(m0 + c * 64 + srow) * K + kt + sk;
            __builtin_amdgcn_global_load_lds(
                (const __attribute__((address_space(1))) void*)ga,
                (__attribute__((address_space(3))) void*)(&As[c * 2048 + tid * 8]),
                16, 0, 0);
            const unsigned short* gb = Bt + (size_t)(n0 + c * 64 + srow) * K + kt + sk;
            __builtin_amdgcn_global_load_lds(
                (const __attribute__((address_space(1))) void*)gb,
                (__attribute__((address_space(3))) void*)(&Bs[c * 2048 + tid * 8]),
                16, 0, 0);
        }
        __syncthreads();

        bf16x8 af[4], bfr[4];
        #pragma unroll
        for (int i = 0; i < 4; ++i) {
            af[i]  = *reinterpret_cast<const bf16x8*>(&As[(wm + i * 16 + l15) * 32 + kg * 8]);
            bfr[i] = *reinterpret_cast<const bf16x8*>(&Bs[(wn + i * 16 + l15) * 32 + kg * 8]);
        }
        #pragma unroll
        for (int i = 0; i < 4; ++i)
            #pragma unroll
            for (int j = 0; j < 4; ++j)
                acc[i][j] = __builtin_amdgcn_mfma_f32_16x16x32_bf16(af[i], bfr[j], acc[i][j], 0, 0, 0);
        __syncthreads();
    }

    const int crow = kg * 4;
    #pragma unroll
    for (int i = 0; i < 4; ++i) {
        #pragma unroll
        for (int j = 0; j < 4; ++j) {
            const int col = n0 + wn + j * 16 + l15;
            const float bb = bias[col];
            #pragma unroll
            for (int r = 0; r < 4; ++r) {
                const int row = m0 + wm + i * 16 + crow + r;
                const float v = acc[i][j][r] + bb;
                if (OUT_BF16)
                    ((unsigned short*)Cv)[(size_t)row * ldc + col] = f2b(v);
                else
                    ((float*)Cv)[(size_t)row * ldc + col] = v;
            }
        }
    }
}

// ---------------------------------------------------------------------------
// Sparse attention (R8 configuration -- best measured). Block = row (512 thr,
// 8 waves = 8 heads). K rows staged into LDS via coalesced global_load_lds
// (1 instr = 1 KB row); V coalesced 128 B per neighbor, issued while K
// staging is in flight. Packed bf16 dot2 score/PV; single barrier pair.
// qkv row: 3072 B = [Q 1024 | K 1024 | V 1024].
// ---------------------------------------------------------------------------
__global__ __launch_bounds__(512) void attn_kernel(
    const unsigned short* __restrict__ qkv,
    const int* __restrict__ nbr_idx,
    const int* __restrict__ nbr_cnt,
    unsigned short* __restrict__ ao)
{
    const int row = blockIdx.x;
    const int b = (row >= S_LEN) ? 1 : 0;
    const int tid = threadIdx.x;
    const int h = tid >> 6;
    const int lane = tid & 63;
    const int j = lane & 31;
    const int half = lane >> 5;

    __shared__ __align__(16) unsigned short K_lds[KMAX][520];  // 33,280 B
    __shared__ unsigned int s_off[KMAX];
    __shared__ unsigned int sQ[N_HEADS][32];
    __shared__ int s_cnt;

    if (tid < KMAX) {
        const int cnt0 = nbr_cnt[row];
        int t = nbr_idx[(size_t)row * KMAX + tid];
        t = (tid < cnt0) ? t : 0;
        s_off[tid] = (unsigned int)t * 3072u;   // qkv row bytes
        if (tid == 0) s_cnt = cnt0;
    }
    if (lane < 32)   // packed bf16 Q per head
        sQ[h][lane] = ((const unsigned int*)(qkv + (size_t)row * 1536 + h * DH))[lane];
    __syncthreads();

    const int cnt = s_cnt;
    const char* qkvb_ = (const char*)qkv + (size_t)b * S_LEN * 3072;

    // --- K staging: wave h stages neighbor rows h*4..h*4+3 (1 KB each) ---
    {
        const int jb = h * 4;
        #pragma unroll
        for (int c = 0; c < 4; ++c) {
            const int jj = jb + c;
            const char* src = qkvb_ + s_off[jj] + 1024 + lane * 16;
            __builtin_amdgcn_global_load_lds(
                (const __attribute__((address_space(1))) void*)src,
                (__attribute__((address_space(3))) void*)(&K_lds[jj][0]),
                16, 0, 0);
        }
    }

    // --- V prefetch from global (coalesced 128 B per neighbor) ---
    const char* vbase_l = qkvb_ + 2048 + h * 128 + lane * 2;
    unsigned int vr[KMAX];
    #pragma unroll
    for (int jj = 0; jj < KMAX; ++jj)
        vr[jj] = *(const unsigned short*)(vbase_l + s_off[jj]);

    __syncthreads();   // drains vmcnt (staging + V) before LDS reads

    // --- score: lane (half, j) reads 32 dims of neighbor j's K from LDS ---
    const uint4* kp = reinterpret_cast<const uint4*>(&K_lds[j][h * 64 + half * 32]);
    uint4 ku[4];
    #pragma unroll
    for (int c = 0; c < 4; ++c) ku[c] = kp[c];

    const unsigned int* qws = &sQ[h][half * 16];
    float partial = 0.f;
    #pragma unroll
    for (int c = 0; c < 4; ++c) {
        partial = dot2bf(ku[c].x, qws[c * 4 + 0], partial);
        partial = dot2bf(ku[c].y, qws[c * 4 + 1], partial);
        partial = dot2bf(ku[c].z, qws[c * 4 + 2], partial);
        partial = dot2bf(ku[c].w, qws[c * 4 + 3], partial);
    }
    partial += __shfl_down(partial, 32, 64);   // lanes 0..31 hold full dots

    // --- softmax over lanes 0..31 ---
    const float sc = (half == 0 && j < cnt) ? partial * 0.125f : -INFINITY;
    float mx = sc;
    #pragma unroll
    for (int off = 16; off; off >>= 1) mx = fmaxf(mx, __shfl_xor(mx, off, 64));
    const float pr = (half == 0 && j < cnt) ? expf(sc - mx) : 0.f;
    float sum = pr;
    #pragma unroll
    for (int off = 16; off; off >>= 1) sum += __shfl_xor(sum, off, 64);
    const float inv = __uint_as_float(
        __builtin_amdgcn_readfirstlane(__float_as_uint(1.f / sum)));

    // --- weights -> packed bf16 pairs (even lanes hold (p_2i, p_2i+1)) ---
    const float pn = __shfl_xor(pr, 1, 64);
    const unsigned int pw = ((unsigned int)f2b(pn) << 16) | f2b(pr);

    // --- PV: per 2 neighbors: 1 readlane + 1 pack + 1 dot2 ---
    float o0 = 0.f, o1 = 0.f;
    #pragma unroll
    for (int i = 0; i < 16; i += 2) {
        const unsigned int w0 = __builtin_amdgcn_readlane(pw, 2 * i);
        const unsigned int w1 = __builtin_amdgcn_readlane(pw, 2 * i + 2);
        const unsigned int vp0 = (vr[2 * i + 1] << 16) | vr[2 * i];
        const unsigned int vp1 = (vr[2 * i + 3] << 16) | vr[2 * i + 2];
        o0 = dot2bf(vp0, w0, o0);
        o1 = dot2bf(vp1, w1, o1);
    }
    const float o = (o0 + o1) * inv;
    ao[(size_t)row * D_MODEL + h * DH + lane] = f2b(o);
}

// ---------------------------------------------------------------------------
extern "C" void kernel_launch(void* const* d_in, const int* in_sizes, int n_in,
                              void* d_out, int out_size, void* d_ws, size_t ws_size,
                              hipStream_t stream) {
    const float* x   = (const float*)d_in[0];
    const float* pos = (const float*)d_in[1];
    const float* Wq  = (const float*)d_in[2];
    const float* bq  = (const float*)d_in[3];
    const float* Wk  = (const float*)d_in[4];
    const float* bk  = (const float*)d_in[5];
    const float* Wv  = (const float*)d_in[6];
    const float* bv  = (const float*)d_in[7];
    const float* Wo  = (const float*)d_in[8];
    const float* bo  = (const float*)d_in[9];
    float* out = (float*)d_out;

    unsigned short* xb   = (unsigned short*)d_ws;                 // 6144*512
    unsigned short* Wt   = xb + (size_t)M_ROWS * 512;             // 2048*512
    float*          bqkv = (float*)(Wt + (size_t)2048 * 512);     // 1536
    unsigned short* qkvb = (unsigned short*)(bqkv + 1536);        // 6144*1536
    unsigned short* aob  = qkvb + (size_t)M_ROWS * 1536;          // 6144*512
    int*            nidx = (int*)(aob + (size_t)M_ROWS * 512);    // 6144*32
    int*            ncnt = nidx + (size_t)M_ROWS * KMAX;          // 6144

    prep_kernel<<<PREP_BLOCKS, 256, 0, stream>>>(
        x, pos, Wq, bq, Wk, bk, Wv, bv, Wo, xb, Wt, bqkv, nidx, ncnt);

    dim3 g1(M_ROWS / 128, 1536 / 128);
    gemm_mfma_kernel<true><<<g1, 256, 0, stream>>>(xb, Wt, bqkv, qkvb, 1536);

    attn_kernel<<<M_ROWS, 512, 0, stream>>>(qkvb, nidx, ncnt, aob);

    dim3 g2(M_ROWS / 128, 512 / 128);
    gemm_mfma_kernel<false><<<g2, 256, 0, stream>>>(aob, Wt + (size_t)1536 * 512, bo, out, 512);
}